// Round 6
// baseline (147.118 us; speedup 1.0000x reference)
//
#include <hip/hip_runtime.h>
#include <stdint.h>

// Top-k (k=50) temperature sampling, bit-matching
// jax.random.categorical(key(42), topk_mask(logits/T, 50)) with
// jax_threefry_partitionable=True.
//
// Round-9 structure: THREE chained kernels (no host sync, ~1 MB d_ws).
// Rounds 4-8 post-mortem: a 256x1024 one-block-per-row scan is pinned at
// ~45us / 600 GB/s regardless of load batching (compiler-level and asm-level
// MLP attempts all left VGPR/time unchanged). The harness's own
// fillBufferAligned (256-thr blocks, huge grid) sustains 6.4 TB/s in the
// same graph -> the memory system is fast for that dispatch shape. So:
// restructure the scan into that shape.
//
//   K1 filter (4096 blk x 256 thr): 16 blocks/row, each scans ~1/16 of the
//      row body (float4-aligned), appends indices of raw logit >= 10.0 into
//      a private 64-slot region + per-block count (LDS atomic only; counts
//      written unconditionally so workspace poison is harmless).
//      Cutoff 10.0: 50th of 50257 N(0,16) draws sits at 12.36 +- 0.17, so
//      top-50 is captured with ~14-sigma margin; ~312 candidates/row total,
//      ~20 +- 4.4 per segment (64-slot overflow is a ~10-sigma event; if it
//      ever happens -> fallback).
//   K2 refine (256 blk x 256 thr): per row, gather candidates, exact IEEE
//      s = l/T keys, exact (s_key,index) rank -> rank < K membership
//      (lax.top_k low-index tie rule), guard (b) boundary-tie check,
//      partitionable-threefry gumbel, argmax with low-index ties ->
//      out[row], flag[row]=1. Guards fail -> flag[row]=0.
//        (a) K <= total <= CAND_CAP and no segment overflow;
//        (b) rank-(K-1) s-key STRICTLY > fkey(10.0/T).
//   K3 fallback (256 blk x 1024 thr): if (flag) return; else the verbatim
//      round-3 two-scan histogram path (exact for arbitrary inputs).

#define VOCAB 50257
#define BATCH 256
#define NT 1024
#define NTF 256
#define NSEG 16
#define SEG4 786          // ceil(12564/16): float4s per segment
#define CAP_SEG 64
#define NBINS 4096
#define CAND_CAP 2048
#define FILTER_VAL 4.0f
#define SPEC_VAL 10.0f

__device__ __forceinline__ uint32_t rotl32(uint32_t v, int r) {
  return (v << r) | (v >> (32 - r));
}

// JAX Threefry-2x32-20, key = (0, 42)
__device__ __forceinline__ void threefry2x32_42(uint32_t& x0, uint32_t& x1) {
  const uint32_t ks0 = 0u;
  const uint32_t ks1 = 42u;
  const uint32_t ks2 = ks0 ^ ks1 ^ 0x1BD11BDAu;
  x0 += ks0; x1 += ks1;
#define TF_R(r) { x0 += x1; x1 = rotl32(x1, (r)); x1 ^= x0; }
  TF_R(13) TF_R(15) TF_R(26) TF_R(6)
  x0 += ks1; x1 += ks2 + 1u;
  TF_R(17) TF_R(29) TF_R(16) TF_R(24)
  x0 += ks2; x1 += ks0 + 2u;
  TF_R(13) TF_R(15) TF_R(26) TF_R(6)
  x0 += ks0; x1 += ks1 + 3u;
  TF_R(17) TF_R(29) TF_R(16) TF_R(24)
  x0 += ks1; x1 += ks2 + 4u;
  TF_R(13) TF_R(15) TF_R(26) TF_R(6)
  x0 += ks2; x1 += ks0 + 5u;
#undef TF_R
}

// Gumbel noise at flat index i, jax_threefry_partitionable=True:
// counter = u64 flat index -> (hi32=0, lo32=i), bits = out0 ^ out1.
__device__ __forceinline__ float gumbel_at(uint32_t flat) {
  uint32_t x0 = 0u, x1 = flat;
  threefry2x32_42(x0, x1);
  uint32_t bits = x0 ^ x1;
  uint32_t fb = (bits >> 9) | 0x3f800000u;
  float f = __uint_as_float(fb) - 1.0f;          // exact
  float u = fmaxf(f, 1.17549435e-38f);
  float t = (float)log((double)u);               // correctly-rounded fp32 path
  float g = (float)(-log((double)(-t)));
  return g;
}

// Monotone float->uint32 key (no NaNs in data).
__device__ __forceinline__ uint32_t fkey(float x) {
  uint32_t u = __float_as_uint(x);
  return (u & 0x80000000u) ? ~u : (u | 0x80000000u);
}

// ---- K1: streaming filter, fill-shaped dispatch ----
extern "C" __global__ void __launch_bounds__(NTF)
filter_kernel(const float* __restrict__ logits,
              int* __restrict__ cnt,          // [BATCH*NSEG]
              int* __restrict__ cand) {       // [BATCH*NSEG][CAP_SEG]
  const int b = blockIdx.x;                   // 0..BATCH*NSEG-1
  const int row = b >> 4;
  const int seg = b & 15;
  const int tid = threadIdx.x;
  const float* rowp = logits + (size_t)row * VOCAB;

  // rows are only 4B-aligned (VOCAB%4==1): scalar prologue to 16B.
  const int pc = (4 - (row & 3)) & 3;
  const int nv4 = (VOCAB - pc) >> 2;          // 12563 or 12564
  const int tailbase = pc + (nv4 << 2);
  const int tailc = VOCAB - tailbase;         // 0..3
  const float4* body = (const float4*)(rowp + pc);

  __shared__ int lcnt;
  if (tid == 0) lcnt = 0;
  __syncthreads();

  int* myc = cand + (b << 6);                 // this block's 64 slots
  const int st = seg * SEG4;
  const int en = min(nv4, st + SEG4);
  for (int v = st + tid; v < en; v += NTF) {
    float4 x = body[v];
    int base = pc + (v << 2);
    if (x.x >= SPEC_VAL) { int p = atomicAdd(&lcnt, 1); if (p < CAP_SEG) myc[p] = base; }
    if (x.y >= SPEC_VAL) { int p = atomicAdd(&lcnt, 1); if (p < CAP_SEG) myc[p] = base + 1; }
    if (x.z >= SPEC_VAL) { int p = atomicAdd(&lcnt, 1); if (p < CAP_SEG) myc[p] = base + 2; }
    if (x.w >= SPEC_VAL) { int p = atomicAdd(&lcnt, 1); if (p < CAP_SEG) myc[p] = base + 3; }
  }
  if (seg == 0 && tid < pc) {
    if (rowp[tid] >= SPEC_VAL) { int p = atomicAdd(&lcnt, 1); if (p < CAP_SEG) myc[p] = tid; }
  }
  if (seg == NSEG - 1 && tid < tailc) {
    if (rowp[tailbase + tid] >= SPEC_VAL) {
      int p = atomicAdd(&lcnt, 1); if (p < CAP_SEG) myc[p] = tailbase + tid;
    }
  }
  __syncthreads();
  if (tid == 0) cnt[b] = lcnt;                // real count (may exceed CAP_SEG)
}

// ---- K2: per-row exact refine over ~312 candidates ----
extern "C" __global__ void __launch_bounds__(NTF)
refine_kernel(const float* __restrict__ logits,
              const float* __restrict__ temp_p,
              const int* __restrict__ topk_p,
              int* __restrict__ out,
              const int* __restrict__ cnt,
              const int* __restrict__ cand,
              int* __restrict__ flags) {
  const int row = blockIdx.x;
  const int tid = threadIdx.x;
  const int lane = tid & 63;
  const int wave = tid >> 6;

  __shared__ int scnt[NSEG], soff[NSEG];
  __shared__ int sh_total, sh_ok;
  __shared__ unsigned ckey[CAND_CAP];
  __shared__ int cidx[CAND_CAP];
  __shared__ float wbv[4];
  __shared__ int wbi[4];

  if (tid < NSEG) scnt[tid] = cnt[(row << 4) + tid];
  if (tid == 0) sh_ok = 0;
  __syncthreads();
  if (tid == 0) {
    int acc = 0; int ovf = 0;
    for (int s = 0; s < NSEG; ++s) {
      soff[s] = acc;
      if (scnt[s] > CAP_SEG) ovf = 1;
      acc += scnt[s];
    }
    sh_total = ovf ? -1 : acc;
  }
  __syncthreads();
  const int total = sh_total;
  const int K = topk_p[0];
  const float temp = temp_p[0];

  const bool ok_path = (total >= K && total <= CAND_CAP);   // block-uniform
  if (ok_path) {
    // gather candidates: 16 threads per segment
    {
      int s = tid >> 4, j0 = tid & 15;
      const int* src = cand + (((row << 4) + s) << 6);
      for (int j = j0; j < scnt[s]; j += 16) cidx[soff[s] + j] = src[j];
    }
    __syncthreads();
    const float* rowp = logits + (size_t)row * VOCAB;
    for (int c = tid; c < total; c += NTF) {
      ckey[c] = fkey(rowp[cidx[c]] / temp);   // IEEE fp32 div, matches reference
    }
    __syncthreads();

    float bestv = -__builtin_huge_valf();
    int besti = 0x7fffffff;
    const uint32_t cutkey = fkey(SPEC_VAL / temp);
    for (int c = tid; c < total; c += NTF) {
      const uint32_t mk = ckey[c];
      const int mi = cidx[c];
      int rank = 0;
      for (int j = 0; j < total; ++j) {
        uint32_t k = ckey[j];
        rank += (k > mk || (k == mk && cidx[j] < mi)) ? 1 : 0;
      }
      if (rank == K - 1) {
        // guard (b): K-th s-key strictly above cutoff s-key => no sub-cutoff
        // element can reach or tie the top-K boundary (low-index tie rule).
        sh_ok = (mk > cutkey) ? 1 : 0;        // unique writer
      }
      if (rank < K) {                         // exact lax.top_k membership
        float s = rowp[mi] / temp;
        float v = s + gumbel_at((uint32_t)row * (uint32_t)VOCAB + (uint32_t)mi);
        if (v > bestv || (v == bestv && mi < besti)) { bestv = v; besti = mi; }
      }
    }
    __syncthreads();
    if (sh_ok) {
      for (int off = 32; off > 0; off >>= 1) {
        float v2 = __shfl_down(bestv, off);
        int i2 = __shfl_down(besti, off);
        if (v2 > bestv || (v2 == bestv && i2 < besti)) { bestv = v2; besti = i2; }
      }
      if (lane == 0) { wbv[wave] = bestv; wbi[wave] = besti; }
      __syncthreads();
      if (tid == 0) {
        float bv = wbv[0]; int bi = wbi[0];
        for (int w = 1; w < 4; ++w) {
          if (wbv[w] > bv || (wbv[w] == bv && wbi[w] < bi)) { bv = wbv[w]; bi = wbi[w]; }
        }
        out[row] = bi;
        flags[row] = 1;
      }
    } else if (tid == 0) {
      flags[row] = 0;
    }
  } else if (tid == 0) {
    flags[row] = 0;
  }
}

// ---- K3: exact fallback (verbatim round-3 two-scan histogram path) ----
extern "C" __global__ void __launch_bounds__(NT)
fallback_kernel(const float* __restrict__ logits,
                const float* __restrict__ temp_p,
                const int* __restrict__ topk_p,
                int* __restrict__ out,
                const int* __restrict__ flags) {
  const int row = blockIdx.x;
  if (flags[row]) return;                     // block-uniform early exit

  const int tid = threadIdx.x;
  const float temp = temp_p[0];
  const int K = topk_p[0];
  const float* rowp = logits + (size_t)row * VOCAB;

  const int pc = (4 - (row & 3)) & 3;
  const int nv4 = (VOCAB - pc) >> 2;
  const int tailbase = pc + (nv4 << 2);
  const int tailc = VOCAB - tailbase;
  const float4* body = (const float4*)(rowp + pc);

  __shared__ unsigned hist[NBINS];
  __shared__ unsigned wtot[16];
  __shared__ unsigned aboveWave[16];
  __shared__ int sh_tb, sh_total, sh_cnt;
  __shared__ unsigned ckey[CAND_CAP];
  __shared__ int cidx[CAND_CAP];
  __shared__ float wbv[16];
  __shared__ int wbi[16];

  const int lane = tid & 63;
  const int wave = tid >> 6;

  float bestv = -__builtin_huge_valf();
  int besti = 0x7fffffff;

  uint32_t filt = fkey(FILTER_VAL);
  int tb = 0;
  for (;;) {
    for (int b = tid; b < NBINS; b += NT) hist[b] = 0u;
    __syncthreads();
    if (tid < pc) {
      uint32_t k = fkey(rowp[tid]);
      if (k >= filt) atomicAdd(&hist[k >> 20], 1u);
    }
    for (int w = tid; w < nv4; w += NT) {
      float4 x = body[w];
      uint32_t k0 = fkey(x.x), k1 = fkey(x.y), k2 = fkey(x.z), k3 = fkey(x.w);
      if (k0 >= filt) atomicAdd(&hist[k0 >> 20], 1u);
      if (k1 >= filt) atomicAdd(&hist[k1 >> 20], 1u);
      if (k2 >= filt) atomicAdd(&hist[k2 >> 20], 1u);
      if (k3 >= filt) atomicAdd(&hist[k3 >> 20], 1u);
    }
    if (tid < tailc) {
      uint32_t k = fkey(rowp[tailbase + tid]);
      if (k >= filt) atomicAdd(&hist[k >> 20], 1u);
    }
    __syncthreads();

    unsigned p = hist[4 * tid] + hist[4 * tid + 1] + hist[4 * tid + 2] + hist[4 * tid + 3];
    unsigned vv = p;
    for (int off = 1; off < 64; off <<= 1) {
      unsigned o = (unsigned)__shfl_down((int)vv, off);
      if (lane + off < 64) vv += o;           // inclusive suffix sum within wave
    }
    if (lane == 0) wtot[wave] = vv;
    __syncthreads();
    if (tid == 0) {
      unsigned acc = 0;
      for (int w = 15; w >= 0; --w) { aboveWave[w] = acc; acc += wtot[w]; }
      sh_total = (int)acc;
    }
    __syncthreads();
    unsigned above = aboveWave[wave] + (vv - p);
    if (above < (unsigned)K && above + p >= (unsigned)K) {
      int need = K - (int)above;
      for (int b = 3; b >= 0; --b) {
        unsigned c = hist[4 * tid + b];
        if (c >= (unsigned)need) { sh_tb = 4 * tid + b; break; }
        need -= (int)c;
      }
    }
    __syncthreads();
    if (sh_total >= K) { tb = sh_tb; break; }
    filt = 0u;
    __syncthreads();
  }

  const uint32_t cutk = (uint32_t)max(tb - 1, 0) << 20;
  if (tid == 0) sh_cnt = 0;
  __syncthreads();
  if (tid < pc) {
    if (fkey(rowp[tid]) >= cutk) {
      int p = atomicAdd(&sh_cnt, 1);
      if (p < CAND_CAP) cidx[p] = tid;
    }
  }
  for (int w = tid; w < nv4; w += NT) {
    float4 x = body[w];
    int base = pc + (w << 2);
    if (fkey(x.x) >= cutk) { int p = atomicAdd(&sh_cnt, 1); if (p < CAND_CAP) cidx[p] = base; }
    if (fkey(x.y) >= cutk) { int p = atomicAdd(&sh_cnt, 1); if (p < CAND_CAP) cidx[p] = base + 1; }
    if (fkey(x.z) >= cutk) { int p = atomicAdd(&sh_cnt, 1); if (p < CAND_CAP) cidx[p] = base + 2; }
    if (fkey(x.w) >= cutk) { int p = atomicAdd(&sh_cnt, 1); if (p < CAND_CAP) cidx[p] = base + 3; }
  }
  if (tid < tailc) {
    if (fkey(rowp[tailbase + tid]) >= cutk) {
      int p = atomicAdd(&sh_cnt, 1);
      if (p < CAND_CAP) cidx[p] = tailbase + tid;
    }
  }
  __syncthreads();
  const int C = min(sh_cnt, CAND_CAP);

  if (tid < C) {
    int idx = cidx[tid];
    float s = rowp[idx] / temp;
    ckey[tid] = fkey(s);
  }
  __syncthreads();

  if (tid < C) {
    const uint32_t mk = ckey[tid];
    const int mi = cidx[tid];
    int rank = 0;
    for (int j = 0; j < C; ++j) {
      uint32_t k = ckey[j];
      rank += (k > mk || (k == mk && cidx[j] < mi)) ? 1 : 0;
    }
    if (rank < K) {
      float s = rowp[mi] / temp;
      float v2 = s + gumbel_at((uint32_t)row * (uint32_t)VOCAB + (uint32_t)mi);
      bestv = v2; besti = mi;
    }
  }
  __syncthreads();

  for (int off = 32; off > 0; off >>= 1) {
    float v2 = __shfl_down(bestv, off);
    int i2 = __shfl_down(besti, off);
    if (v2 > bestv || (v2 == bestv && i2 < besti)) { bestv = v2; besti = i2; }
  }
  if (lane == 0) { wbv[wave] = bestv; wbi[wave] = besti; }
  __syncthreads();
  if (tid == 0) {
    float bv = wbv[0];
    int bi = wbi[0];
    for (int w = 1; w < 16; ++w) {
      if (wbv[w] > bv || (wbv[w] == bv && wbi[w] < bi)) { bv = wbv[w]; bi = wbi[w]; }
    }
    out[row] = bi;
  }
}

extern "C" void kernel_launch(void* const* d_in, const int* in_sizes, int n_in,
                              void* d_out, int out_size, void* d_ws, size_t ws_size,
                              hipStream_t stream) {
  const float* logits = (const float*)d_in[0];
  const float* temp_p = (const float*)d_in[1];
  const int* topk_p = (const int*)d_in[2];
  int* out = (int*)d_out;

  // workspace layout: cnt[4096] | cand[4096][64] | flags[256]  (~1.02 MB)
  int* cnt = (int*)d_ws;
  int* cand = cnt + BATCH * NSEG;
  int* flags = cand + BATCH * NSEG * CAP_SEG;

  hipLaunchKernelGGL(filter_kernel, dim3(BATCH * NSEG), dim3(NTF), 0, stream,
                     logits, cnt, cand);
  hipLaunchKernelGGL(refine_kernel, dim3(BATCH), dim3(NTF), 0, stream,
                     logits, temp_p, topk_p, out, cnt, cand, flags);
  hipLaunchKernelGGL(fallback_kernel, dim3(BATCH), dim3(NT), 0, stream,
                     logits, temp_p, topk_p, out, flags);
}

// Round 7
// 95.805 us; speedup vs baseline: 1.5356x; 1.5356x over previous
//
#include <hip/hip_runtime.h>
#include <stdint.h>

// Top-k (k=50) temperature sampling, bit-matching
// jax.random.categorical(key(42), topk_mask(logits/T, 50)) with
// jax_threefry_partitionable=True.
//
// Round-10 structure: THREE chained kernels (no host sync, ~1 MB d_ws).
//   K1 filter (4096 blk x 256 thr, fill-shaped -- proven fast in r9): 16
//      blocks/row, each scans ~1/16 of the row body, appends indices of raw
//      logit >= 10.0 into a private 64-slot region + per-block count.
//      Cutoff 10.0: 50th of 50257 N(0,16) draws sits at 12.36 +- 0.17 ->
//      ~312 candidates/row, ~20 +- 4.4 per segment.
//   K2 refine (256 blk x 256 thr) -- REWRITTEN this round. r9's O(C^2)
//      rank loop was 312 serial ds_reads/thread (~120cy each, m117) -> 62us.
//      Now: exact histogram select over the ~312 candidates:
//        bin = min(1023, (key - cutkey) >> 15)   (monotone; key >= cutkey
//        because IEEE rounded division by T>0 is monotone)
//        suffix-scan -> threshold bin tb, need = K - above;
//        bins > tb: in top-K; bin == tb (~3-6 members): exact (key,index)
//        sub-rank, keep rank < need  == exact lax.top_k low-index tie rule.
//      Guard (b): rank-(need-1) boundary member must have key STRICTLY >
//      cutkey (automatic if tb > 0). s recovered bit-exactly from key
//      (fkey is a bijection), gumbel via partitionable threefry, argmax
//      with low-index ties -> out[row], flags[row]=1.
//      Guards: (a) K <= total <= CAND_CAP, no segment overflow;
//              (m) boundary-bin population <= 256; (b) as above.
//      Any guard fails -> flags[row]=0.
//   K3 fallback (256 blk x 1024 thr): if (flag) return; else verbatim
//      round-3 two-scan histogram path (exact for arbitrary inputs).

#define VOCAB 50257
#define BATCH 256
#define NT 1024
#define NTF 256
#define NSEG 16
#define SEG4 786          // ceil(12564/16): float4s per segment
#define CAP_SEG 64
#define NBINS 4096
#define HBINS 1024
#define BSHIFT 15
#define BCAP 256
#define CAND_CAP 2048
#define FILTER_VAL 4.0f
#define SPEC_VAL 10.0f

__device__ __forceinline__ uint32_t rotl32(uint32_t v, int r) {
  return (v << r) | (v >> (32 - r));
}

// JAX Threefry-2x32-20, key = (0, 42)
__device__ __forceinline__ void threefry2x32_42(uint32_t& x0, uint32_t& x1) {
  const uint32_t ks0 = 0u;
  const uint32_t ks1 = 42u;
  const uint32_t ks2 = ks0 ^ ks1 ^ 0x1BD11BDAu;
  x0 += ks0; x1 += ks1;
#define TF_R(r) { x0 += x1; x1 = rotl32(x1, (r)); x1 ^= x0; }
  TF_R(13) TF_R(15) TF_R(26) TF_R(6)
  x0 += ks1; x1 += ks2 + 1u;
  TF_R(17) TF_R(29) TF_R(16) TF_R(24)
  x0 += ks2; x1 += ks0 + 2u;
  TF_R(13) TF_R(15) TF_R(26) TF_R(6)
  x0 += ks0; x1 += ks1 + 3u;
  TF_R(17) TF_R(29) TF_R(16) TF_R(24)
  x0 += ks1; x1 += ks2 + 4u;
  TF_R(13) TF_R(15) TF_R(26) TF_R(6)
  x0 += ks2; x1 += ks0 + 5u;
#undef TF_R
}

// Gumbel noise at flat index i, jax_threefry_partitionable=True:
// counter = u64 flat index -> (hi32=0, lo32=i), bits = out0 ^ out1.
__device__ __forceinline__ float gumbel_at(uint32_t flat) {
  uint32_t x0 = 0u, x1 = flat;
  threefry2x32_42(x0, x1);
  uint32_t bits = x0 ^ x1;
  uint32_t fb = (bits >> 9) | 0x3f800000u;
  float f = __uint_as_float(fb) - 1.0f;          // exact
  float u = fmaxf(f, 1.17549435e-38f);
  float t = (float)log((double)u);               // correctly-rounded fp32 path
  float g = (float)(-log((double)(-t)));
  return g;
}

// Monotone float->uint32 key (no NaNs in data).
__device__ __forceinline__ uint32_t fkey(float x) {
  uint32_t u = __float_as_uint(x);
  return (u & 0x80000000u) ? ~u : (u | 0x80000000u);
}

// Exact inverse of fkey (bijection).
__device__ __forceinline__ float inv_fkey(uint32_t k) {
  uint32_t u = (k & 0x80000000u) ? (k ^ 0x80000000u) : ~k;
  return __uint_as_float(u);
}

// ---- K1: streaming filter, fill-shaped dispatch (unchanged from r9) ----
extern "C" __global__ void __launch_bounds__(NTF)
filter_kernel(const float* __restrict__ logits,
              int* __restrict__ cnt,          // [BATCH*NSEG]
              int* __restrict__ cand) {       // [BATCH*NSEG][CAP_SEG]
  const int b = blockIdx.x;                   // 0..BATCH*NSEG-1
  const int row = b >> 4;
  const int seg = b & 15;
  const int tid = threadIdx.x;
  const float* rowp = logits + (size_t)row * VOCAB;

  const int pc = (4 - (row & 3)) & 3;
  const int nv4 = (VOCAB - pc) >> 2;          // 12563 or 12564
  const int tailbase = pc + (nv4 << 2);
  const int tailc = VOCAB - tailbase;         // 0..3
  const float4* body = (const float4*)(rowp + pc);

  __shared__ int lcnt;
  if (tid == 0) lcnt = 0;
  __syncthreads();

  int* myc = cand + (b << 6);                 // this block's 64 slots
  const int st = seg * SEG4;
  const int en = min(nv4, st + SEG4);
  for (int v = st + tid; v < en; v += NTF) {
    float4 x = body[v];
    int base = pc + (v << 2);
    if (x.x >= SPEC_VAL) { int p = atomicAdd(&lcnt, 1); if (p < CAP_SEG) myc[p] = base; }
    if (x.y >= SPEC_VAL) { int p = atomicAdd(&lcnt, 1); if (p < CAP_SEG) myc[p] = base + 1; }
    if (x.z >= SPEC_VAL) { int p = atomicAdd(&lcnt, 1); if (p < CAP_SEG) myc[p] = base + 2; }
    if (x.w >= SPEC_VAL) { int p = atomicAdd(&lcnt, 1); if (p < CAP_SEG) myc[p] = base + 3; }
  }
  if (seg == 0 && tid < pc) {
    if (rowp[tid] >= SPEC_VAL) { int p = atomicAdd(&lcnt, 1); if (p < CAP_SEG) myc[p] = tid; }
  }
  if (seg == NSEG - 1 && tid < tailc) {
    if (rowp[tailbase + tid] >= SPEC_VAL) {
      int p = atomicAdd(&lcnt, 1); if (p < CAP_SEG) myc[p] = tailbase + tid;
    }
  }
  __syncthreads();
  if (tid == 0) cnt[b] = lcnt;                // real count (may exceed CAP_SEG)
}

// ---- K2: per-row exact refine, histogram-select (rewritten) ----
extern "C" __global__ void __launch_bounds__(NTF)
refine_kernel(const float* __restrict__ logits,
              const float* __restrict__ temp_p,
              const int* __restrict__ topk_p,
              int* __restrict__ out,
              const int* __restrict__ cnt,
              const int* __restrict__ cand,
              int* __restrict__ flags) {
  const int row = blockIdx.x;
  const int tid = threadIdx.x;
  const int lane = tid & 63;
  const int wave = tid >> 6;

  __shared__ int scnt[NSEG], soff[NSEG];
  __shared__ int sh_total, sh_ok, sh_tb, sh_need, sh_bcnt;
  __shared__ unsigned ckey[CAND_CAP];
  __shared__ int cidx[CAND_CAP];
  __shared__ unsigned hist[HBINS];
  __shared__ unsigned bkey[BCAP];
  __shared__ int bidx[BCAP];
  __shared__ unsigned wtot[4], aboveWave[4];
  __shared__ float wbv[4];
  __shared__ int wbi[4];

  const int K = topk_p[0];
  const float temp = temp_p[0];

  if (tid < NSEG) scnt[tid] = cnt[(row << 4) + tid];
  if (tid == 0) { sh_ok = 0; sh_bcnt = 0; }
  for (int b = tid; b < HBINS; b += NTF) hist[b] = 0u;
  __syncthreads();
  if (tid == 0) {
    int acc = 0, ovf = 0;
    for (int s = 0; s < NSEG; ++s) {
      soff[s] = acc;
      if (scnt[s] > CAP_SEG) ovf = 1;
      acc += scnt[s];
    }
    sh_total = ovf ? -1 : acc;
  }
  __syncthreads();
  const int total = sh_total;

  if (!(total >= K && total <= CAND_CAP)) {   // guard (a), block-uniform
    if (tid == 0) flags[row] = 0;
    return;
  }

  // gather candidates: 16 threads per segment
  {
    int s = tid >> 4, j0 = tid & 15;
    const int* src = cand + (((row << 4) + s) << 6);
    for (int j = j0; j < scnt[s]; j += 16) cidx[soff[s] + j] = src[j];
  }
  __syncthreads();

  // exact s-keys + histogram. All keys >= cutkey (monotone rounded division).
  const float* rowp = logits + (size_t)row * VOCAB;
  const uint32_t cutkey = fkey(SPEC_VAL / temp);
  for (int c = tid; c < total; c += NTF) {
    unsigned k = fkey(rowp[cidx[c]] / temp);  // IEEE fp32 div, matches reference
    ckey[c] = k;
    unsigned bin = min((unsigned)(HBINS - 1), (k - cutkey) >> BSHIFT);
    atomicAdd(&hist[bin], 1u);
  }
  __syncthreads();

  // suffix-scan over 1024 bins: thread t owns bins [4t, 4t+3] (ascending key)
  {
    unsigned p = hist[4 * tid] + hist[4 * tid + 1] + hist[4 * tid + 2] + hist[4 * tid + 3];
    unsigned vv = p;
    for (int off = 1; off < 64; off <<= 1) {
      unsigned o = (unsigned)__shfl_down((int)vv, off);
      if (lane + off < 64) vv += o;           // inclusive suffix sum within wave
    }
    if (lane == 0) wtot[wave] = vv;
    __syncthreads();
    if (tid == 0) {
      unsigned acc = 0;
      for (int w = 3; w >= 0; --w) { aboveWave[w] = acc; acc += wtot[w]; }
    }
    __syncthreads();
    unsigned above = aboveWave[wave] + (vv - p);  // count in bins strictly above chunk
    if (above < (unsigned)K && above + p >= (unsigned)K) {  // unique crossing thread
      int need = K - (int)above;
      for (int b = 3; b >= 0; --b) {
        unsigned c = hist[4 * tid + b];
        if (c >= (unsigned)need) { sh_tb = 4 * tid + b; sh_need = need; break; }
        need -= (int)c;
      }
    }
  }
  __syncthreads();
  const int tb = sh_tb;
  const int need = sh_need;

  // collect boundary-bin members
  for (int c = tid; c < total; c += NTF) {
    unsigned k = ckey[c];
    unsigned bin = min((unsigned)(HBINS - 1), (k - cutkey) >> BSHIFT);
    if ((int)bin == tb) {
      int p = atomicAdd(&sh_bcnt, 1);
      if (p < BCAP) { bkey[p] = k; bidx[p] = cidx[c]; }
    }
  }
  __syncthreads();
  const int m = sh_bcnt;                      // == hist[tb] >= need
  if (m > BCAP) {                             // guard (m), block-uniform
    if (tid == 0) flags[row] = 0;
    return;
  }

  float bestv = -__builtin_huge_valf();
  int besti = 0x7fffffff;

  // exact sub-rank within the boundary bin (m small); exactly one member has
  // rank need-1 (strict total order on (key desc, idx asc)) -> guard (b).
  if (tid < m) {
    const unsigned mk = bkey[tid];
    const int mi = bidx[tid];
    int rank = 0;
    for (int j = 0; j < m; ++j) {
      unsigned k = bkey[j];
      rank += (k > mk || (k == mk && bidx[j] < mi)) ? 1 : 0;
    }
    if (rank == need - 1) {
      // guard (b): K-th s-key strictly above cutoff s-key => no sub-cutoff
      // element can reach or tie the top-K boundary (low-index tie rule).
      sh_ok = (tb > 0 || mk > cutkey) ? 1 : 0;
    }
    if (rank < need) {                        // boundary member of top-K
      float s = inv_fkey(mk);                 // bit-exact l/temp
      float v = s + gumbel_at((uint32_t)row * (uint32_t)VOCAB + (uint32_t)mi);
      if (v > bestv || (v == bestv && mi < besti)) { bestv = v; besti = mi; }
    }
  }

  // members in bins strictly above tb are all in top-K
  for (int c = tid; c < total; c += NTF) {
    unsigned k = ckey[c];
    unsigned bin = min((unsigned)(HBINS - 1), (k - cutkey) >> BSHIFT);
    if ((int)bin > tb) {
      int mi = cidx[c];
      float s = inv_fkey(k);
      float v = s + gumbel_at((uint32_t)row * (uint32_t)VOCAB + (uint32_t)mi);
      if (v > bestv || (v == bestv && mi < besti)) { bestv = v; besti = mi; }
    }
  }
  __syncthreads();                            // sh_ok settled
  if (!sh_ok) {                               // block-uniform
    if (tid == 0) flags[row] = 0;
    return;
  }

  // argmax reduction: wave shuffle + 4-way LDS combine
  for (int off = 32; off > 0; off >>= 1) {
    float v2 = __shfl_down(bestv, off);
    int i2 = __shfl_down(besti, off);
    if (v2 > bestv || (v2 == bestv && i2 < besti)) { bestv = v2; besti = i2; }
  }
  if (lane == 0) { wbv[wave] = bestv; wbi[wave] = besti; }
  __syncthreads();
  if (tid == 0) {
    float bv = wbv[0]; int bi = wbi[0];
    for (int w = 1; w < 4; ++w) {
      if (wbv[w] > bv || (wbv[w] == bv && wbi[w] < bi)) { bv = wbv[w]; bi = wbi[w]; }
    }
    out[row] = bi;
    flags[row] = 1;
  }
}

// ---- K3: exact fallback (verbatim round-3 two-scan histogram path) ----
extern "C" __global__ void __launch_bounds__(NT)
fallback_kernel(const float* __restrict__ logits,
                const float* __restrict__ temp_p,
                const int* __restrict__ topk_p,
                int* __restrict__ out,
                const int* __restrict__ flags) {
  const int row = blockIdx.x;
  if (flags[row]) return;                     // block-uniform early exit

  const int tid = threadIdx.x;
  const float temp = temp_p[0];
  const int K = topk_p[0];
  const float* rowp = logits + (size_t)row * VOCAB;

  const int pc = (4 - (row & 3)) & 3;
  const int nv4 = (VOCAB - pc) >> 2;
  const int tailbase = pc + (nv4 << 2);
  const int tailc = VOCAB - tailbase;
  const float4* body = (const float4*)(rowp + pc);

  __shared__ unsigned hist[NBINS];
  __shared__ unsigned wtot[16];
  __shared__ unsigned aboveWave[16];
  __shared__ int sh_tb, sh_total, sh_cnt;
  __shared__ unsigned ckey[CAND_CAP];
  __shared__ int cidx[CAND_CAP];
  __shared__ float wbv[16];
  __shared__ int wbi[16];

  const int lane = tid & 63;
  const int wave = tid >> 6;

  float bestv = -__builtin_huge_valf();
  int besti = 0x7fffffff;

  uint32_t filt = fkey(FILTER_VAL);
  int tb = 0;
  for (;;) {
    for (int b = tid; b < NBINS; b += NT) hist[b] = 0u;
    __syncthreads();
    if (tid < pc) {
      uint32_t k = fkey(rowp[tid]);
      if (k >= filt) atomicAdd(&hist[k >> 20], 1u);
    }
    for (int w = tid; w < nv4; w += NT) {
      float4 x = body[w];
      uint32_t k0 = fkey(x.x), k1 = fkey(x.y), k2 = fkey(x.z), k3 = fkey(x.w);
      if (k0 >= filt) atomicAdd(&hist[k0 >> 20], 1u);
      if (k1 >= filt) atomicAdd(&hist[k1 >> 20], 1u);
      if (k2 >= filt) atomicAdd(&hist[k2 >> 20], 1u);
      if (k3 >= filt) atomicAdd(&hist[k3 >> 20], 1u);
    }
    if (tid < tailc) {
      uint32_t k = fkey(rowp[tailbase + tid]);
      if (k >= filt) atomicAdd(&hist[k >> 20], 1u);
    }
    __syncthreads();

    unsigned p = hist[4 * tid] + hist[4 * tid + 1] + hist[4 * tid + 2] + hist[4 * tid + 3];
    unsigned vv = p;
    for (int off = 1; off < 64; off <<= 1) {
      unsigned o = (unsigned)__shfl_down((int)vv, off);
      if (lane + off < 64) vv += o;           // inclusive suffix sum within wave
    }
    if (lane == 0) wtot[wave] = vv;
    __syncthreads();
    if (tid == 0) {
      unsigned acc = 0;
      for (int w = 15; w >= 0; --w) { aboveWave[w] = acc; acc += wtot[w]; }
      sh_total = (int)acc;
    }
    __syncthreads();
    unsigned above = aboveWave[wave] + (vv - p);
    if (above < (unsigned)K && above + p >= (unsigned)K) {
      int need = K - (int)above;
      for (int b = 3; b >= 0; --b) {
        unsigned c = hist[4 * tid + b];
        if (c >= (unsigned)need) { sh_tb = 4 * tid + b; break; }
        need -= (int)c;
      }
    }
    __syncthreads();
    if (sh_total >= K) { tb = sh_tb; break; }
    filt = 0u;
    __syncthreads();
  }

  const uint32_t cutk = (uint32_t)max(tb - 1, 0) << 20;
  if (tid == 0) sh_cnt = 0;
  __syncthreads();
  if (tid < pc) {
    if (fkey(rowp[tid]) >= cutk) {
      int p = atomicAdd(&sh_cnt, 1);
      if (p < CAND_CAP) cidx[p] = tid;
    }
  }
  for (int w = tid; w < nv4; w += NT) {
    float4 x = body[w];
    int base = pc + (w << 2);
    if (fkey(x.x) >= cutk) { int p = atomicAdd(&sh_cnt, 1); if (p < CAND_CAP) cidx[p] = base; }
    if (fkey(x.y) >= cutk) { int p = atomicAdd(&sh_cnt, 1); if (p < CAND_CAP) cidx[p] = base + 1; }
    if (fkey(x.z) >= cutk) { int p = atomicAdd(&sh_cnt, 1); if (p < CAND_CAP) cidx[p] = base + 2; }
    if (fkey(x.w) >= cutk) { int p = atomicAdd(&sh_cnt, 1); if (p < CAND_CAP) cidx[p] = base + 3; }
  }
  if (tid < tailc) {
    if (fkey(rowp[tailbase + tid]) >= cutk) {
      int p = atomicAdd(&sh_cnt, 1);
      if (p < CAND_CAP) cidx[p] = tailbase + tid;
    }
  }
  __syncthreads();
  const int C = min(sh_cnt, CAND_CAP);

  if (tid < C) {
    int idx = cidx[tid];
    float s = rowp[idx] / temp;
    ckey[tid] = fkey(s);
  }
  __syncthreads();

  if (tid < C) {
    const uint32_t mk = ckey[tid];
    const int mi = cidx[tid];
    int rank = 0;
    for (int j = 0; j < C; ++j) {
      uint32_t k = ckey[j];
      rank += (k > mk || (k == mk && cidx[j] < mi)) ? 1 : 0;
    }
    if (rank < K) {
      float s = rowp[mi] / temp;
      float v2 = s + gumbel_at((uint32_t)row * (uint32_t)VOCAB + (uint32_t)mi);
      bestv = v2; besti = mi;
    }
  }
  __syncthreads();

  for (int off = 32; off > 0; off >>= 1) {
    float v2 = __shfl_down(bestv, off);
    int i2 = __shfl_down(besti, off);
    if (v2 > bestv || (v2 == bestv && i2 < besti)) { bestv = v2; besti = i2; }
  }
  if (lane == 0) { wbv[wave] = bestv; wbi[wave] = besti; }
  __syncthreads();
  if (tid == 0) {
    float bv = wbv[0];
    int bi = wbi[0];
    for (int w = 1; w < 16; ++w) {
      if (wbv[w] > bv || (wbv[w] == bv && wbi[w] < bi)) { bv = wbv[w]; bi = wbi[w]; }
    }
    out[row] = bi;
  }
}

extern "C" void kernel_launch(void* const* d_in, const int* in_sizes, int n_in,
                              void* d_out, int out_size, void* d_ws, size_t ws_size,
                              hipStream_t stream) {
  const float* logits = (const float*)d_in[0];
  const float* temp_p = (const float*)d_in[1];
  const int* topk_p = (const int*)d_in[2];
  int* out = (int*)d_out;

  // workspace layout: cnt[4096] | cand[4096][64] | flags[256]  (~1.02 MB)
  int* cnt = (int*)d_ws;
  int* cand = cnt + BATCH * NSEG;
  int* flags = cand + BATCH * NSEG * CAP_SEG;

  hipLaunchKernelGGL(filter_kernel, dim3(BATCH * NSEG), dim3(NTF), 0, stream,
                     logits, cnt, cand);
  hipLaunchKernelGGL(refine_kernel, dim3(BATCH), dim3(NTF), 0, stream,
                     logits, temp_p, topk_p, out, cnt, cand, flags);
  hipLaunchKernelGGL(fallback_kernel, dim3(BATCH), dim3(NT), 0, stream,
                     logits, temp_p, topk_p, out, flags);
}

// Round 8
// 94.493 us; speedup vs baseline: 1.5569x; 1.0139x over previous
//
#include <hip/hip_runtime.h>
#include <stdint.h>

// Top-k (k=50) temperature sampling, bit-matching
// jax.random.categorical(key(42), topk_mask(logits/T, 50)) with
// jax_threefry_partitionable=True.
//
// Round-11 structure: TWO chained kernels (no host sync, ~2 MB d_ws).
//   K1 filter (4096 blk x 256 thr, fill-shaped -- proven fast r9/r10): 16
//      blocks/row, each scans ~1/16 of the row body, appends (index, VALUE)
//      of raw logit >= 10.0 into private 64-slot regions + per-block count.
//      Storing the value (it's already in a register) lets K2 avoid all
//      scattered logits gathers. Cutoff 10.0: 50th of 50257 N(0,16) draws
//      sits at 12.36 +- 0.17 -> ~312 candidates/row, ~20 +- 4.4 /segment.
//   K2 refine+fallback FUSED (256 blk x 1024 thr): exact histogram select
//      over the ~312 candidates (r10's rewrite, now 1 bin/thread):
//        key = fkey(val / T)  (IEEE div, bit-identical to reference);
//        bin = min(1023, (key - cutkey) >> 15)  (monotone, key >= cutkey);
//        suffix-scan -> threshold bin tb, need = K - above;
//        bins > tb in top-K; bin == tb: exact (key,index) sub-rank,
//        keep rank < need  == exact lax.top_k low-index tie rule.
//      s recovered bit-exactly from key (fkey bijection), gumbel via
//      partitionable threefry, argmax with low-index ties -> out[row].
//      Guards (all block-uniform): (a) K <= total <= CAND_CAP, no segment
//      overflow; (m) boundary bin <= 256; (b) rank-(need-1) key STRICTLY >
//      cutkey (auto if tb > 0). Any failure -> INLINE verbatim round-3
//      two-scan histogram fallback (exact for arbitrary inputs) -- no
//      third launch, no flags round-trip.

#define VOCAB 50257
#define BATCH 256
#define NT 1024
#define NTF 256
#define NSEG 16
#define SEG4 786          // ceil(12564/16): float4s per segment
#define CAP_SEG 64
#define NBINS 4096
#define HBINS 1024
#define BSHIFT 15
#define BCAP 256
#define CAND_CAP 2048
#define FILTER_VAL 4.0f
#define SPEC_VAL 10.0f

__device__ __forceinline__ uint32_t rotl32(uint32_t v, int r) {
  return (v << r) | (v >> (32 - r));
}

// JAX Threefry-2x32-20, key = (0, 42)
__device__ __forceinline__ void threefry2x32_42(uint32_t& x0, uint32_t& x1) {
  const uint32_t ks0 = 0u;
  const uint32_t ks1 = 42u;
  const uint32_t ks2 = ks0 ^ ks1 ^ 0x1BD11BDAu;
  x0 += ks0; x1 += ks1;
#define TF_R(r) { x0 += x1; x1 = rotl32(x1, (r)); x1 ^= x0; }
  TF_R(13) TF_R(15) TF_R(26) TF_R(6)
  x0 += ks1; x1 += ks2 + 1u;
  TF_R(17) TF_R(29) TF_R(16) TF_R(24)
  x0 += ks2; x1 += ks0 + 2u;
  TF_R(13) TF_R(15) TF_R(26) TF_R(6)
  x0 += ks0; x1 += ks1 + 3u;
  TF_R(17) TF_R(29) TF_R(16) TF_R(24)
  x0 += ks1; x1 += ks2 + 4u;
  TF_R(13) TF_R(15) TF_R(26) TF_R(6)
  x0 += ks2; x1 += ks0 + 5u;
#undef TF_R
}

// Gumbel noise at flat index i, jax_threefry_partitionable=True:
// counter = u64 flat index -> (hi32=0, lo32=i), bits = out0 ^ out1.
__device__ __forceinline__ float gumbel_at(uint32_t flat) {
  uint32_t x0 = 0u, x1 = flat;
  threefry2x32_42(x0, x1);
  uint32_t bits = x0 ^ x1;
  uint32_t fb = (bits >> 9) | 0x3f800000u;
  float f = __uint_as_float(fb) - 1.0f;          // exact
  float u = fmaxf(f, 1.17549435e-38f);
  float t = (float)log((double)u);               // correctly-rounded fp32 path
  float g = (float)(-log((double)(-t)));
  return g;
}

// Monotone float->uint32 key (no NaNs in data).
__device__ __forceinline__ uint32_t fkey(float x) {
  uint32_t u = __float_as_uint(x);
  return (u & 0x80000000u) ? ~u : (u | 0x80000000u);
}

// Exact inverse of fkey (bijection).
__device__ __forceinline__ float inv_fkey(uint32_t k) {
  uint32_t u = (k & 0x80000000u) ? (k ^ 0x80000000u) : ~k;
  return __uint_as_float(u);
}

// ---- K1: streaming filter, fill-shaped dispatch (+ value store) ----
extern "C" __global__ void __launch_bounds__(NTF)
filter_kernel(const float* __restrict__ logits,
              int* __restrict__ cnt,          // [BATCH*NSEG]
              int* __restrict__ cand_idx,     // [BATCH*NSEG][CAP_SEG]
              float* __restrict__ cand_val) { // [BATCH*NSEG][CAP_SEG]
  const int b = blockIdx.x;                   // 0..BATCH*NSEG-1
  const int row = b >> 4;
  const int seg = b & 15;
  const int tid = threadIdx.x;
  const float* rowp = logits + (size_t)row * VOCAB;

  const int pc = (4 - (row & 3)) & 3;
  const int nv4 = (VOCAB - pc) >> 2;          // 12563 or 12564
  const int tailbase = pc + (nv4 << 2);
  const int tailc = VOCAB - tailbase;         // 0..3
  const float4* body = (const float4*)(rowp + pc);

  __shared__ int lcnt;
  if (tid == 0) lcnt = 0;
  __syncthreads();

  int* myi = cand_idx + (b << 6);             // this block's 64 slots
  float* myv = cand_val + (b << 6);
  const int st = seg * SEG4;
  const int en = min(nv4, st + SEG4);
  for (int v = st + tid; v < en; v += NTF) {
    float4 x = body[v];
    int base = pc + (v << 2);
    if (x.x >= SPEC_VAL) { int p = atomicAdd(&lcnt, 1); if (p < CAP_SEG) { myi[p] = base;     myv[p] = x.x; } }
    if (x.y >= SPEC_VAL) { int p = atomicAdd(&lcnt, 1); if (p < CAP_SEG) { myi[p] = base + 1; myv[p] = x.y; } }
    if (x.z >= SPEC_VAL) { int p = atomicAdd(&lcnt, 1); if (p < CAP_SEG) { myi[p] = base + 2; myv[p] = x.z; } }
    if (x.w >= SPEC_VAL) { int p = atomicAdd(&lcnt, 1); if (p < CAP_SEG) { myi[p] = base + 3; myv[p] = x.w; } }
  }
  if (seg == 0 && tid < pc) {
    float x = rowp[tid];
    if (x >= SPEC_VAL) { int p = atomicAdd(&lcnt, 1); if (p < CAP_SEG) { myi[p] = tid; myv[p] = x; } }
  }
  if (seg == NSEG - 1 && tid < tailc) {
    float x = rowp[tailbase + tid];
    if (x >= SPEC_VAL) {
      int p = atomicAdd(&lcnt, 1); if (p < CAP_SEG) { myi[p] = tailbase + tid; myv[p] = x; }
    }
  }
  __syncthreads();
  if (tid == 0) cnt[b] = lcnt;                // real count (may exceed CAP_SEG)
}

// ---- K2: fused refine (histogram select) + inline exact fallback ----
extern "C" __global__ void __launch_bounds__(NT)
refine_kernel(const float* __restrict__ logits,
              const float* __restrict__ temp_p,
              const int* __restrict__ topk_p,
              int* __restrict__ out,
              const int* __restrict__ cnt,
              const int* __restrict__ cand_idx,
              const float* __restrict__ cand_val) {
  const int row = blockIdx.x;
  const int tid = threadIdx.x;
  const int lane = tid & 63;
  const int wave = tid >> 6;

  __shared__ unsigned hist[NBINS];            // refine uses [0..HBINS)
  __shared__ unsigned ckey[CAND_CAP];
  __shared__ int cidx[CAND_CAP];
  __shared__ int scnt[NSEG], soff[NSEG];
  __shared__ int sh_total, sh_ok, sh_tb, sh_need, sh_bcnt, sh_cnt;
  __shared__ unsigned bkey[BCAP];
  __shared__ int bidx[BCAP];
  __shared__ unsigned wtot[16], aboveWave[16];
  __shared__ float wbv[16];
  __shared__ int wbi[16];

  const int K = topk_p[0];
  const float temp = temp_p[0];

  if (tid < NSEG) scnt[tid] = cnt[(row << 4) + tid];
  if (tid == 0) { sh_ok = 0; sh_bcnt = 0; }
  if (tid < HBINS) hist[tid] = 0u;
  __syncthreads();
  if (tid == 0) {
    int acc = 0, ovf = 0;
    for (int s = 0; s < NSEG; ++s) {
      soff[s] = acc;
      if (scnt[s] > CAP_SEG) ovf = 1;
      acc += scnt[s];
    }
    sh_total = ovf ? -1 : acc;
  }
  __syncthreads();
  const int total = sh_total;

  int ok = (total >= K && total <= CAND_CAP) ? 1 : 0;  // guard (a), uniform
  const uint32_t cutkey = fkey(SPEC_VAL / temp);

  float bestv = -__builtin_huge_valf();
  int besti = 0x7fffffff;

  if (ok) {
    // gather + keys: 64 threads per segment; no logits access needed.
    {
      int s = tid >> 6, j0 = tid & 63;
      const int* srci = cand_idx + (((row << 4) + s) << 6);
      const float* srcv = cand_val + (((row << 4) + s) << 6);
      for (int j = j0; j < scnt[s]; j += 64) {
        int o = soff[s] + j;
        cidx[o] = srci[j];
        ckey[o] = fkey(srcv[j] / temp);       // IEEE fp32 div, matches reference
      }
    }
    __syncthreads();
    // histogram over 1024 bins (all keys >= cutkey: monotone rounded div)
    for (int c = tid; c < total; c += NT) {
      unsigned bin = min((unsigned)(HBINS - 1), (ckey[c] - cutkey) >> BSHIFT);
      atomicAdd(&hist[bin], 1u);
    }
    __syncthreads();
    // suffix-scan, 1 bin/thread (ascending key order with tid)
    {
      unsigned p = hist[tid];
      unsigned vv = p;
      for (int off = 1; off < 64; off <<= 1) {
        unsigned o = (unsigned)__shfl_down((int)vv, off);
        if (lane + off < 64) vv += o;         // inclusive suffix sum in wave
      }
      if (lane == 0) wtot[wave] = vv;
      __syncthreads();
      if (tid == 0) {
        unsigned acc = 0;
        for (int w = 15; w >= 0; --w) { aboveWave[w] = acc; acc += wtot[w]; }
      }
      __syncthreads();
      unsigned above = aboveWave[wave] + (vv - p);  // strictly-above count
      if (above < (unsigned)K && above + p >= (unsigned)K) {  // unique thread
        sh_tb = tid; sh_need = K - (int)above;
      }
    }
    __syncthreads();
    const int tb = sh_tb;
    const int need = sh_need;

    // collect boundary-bin members
    for (int c = tid; c < total; c += NT) {
      unsigned k = ckey[c];
      unsigned bin = min((unsigned)(HBINS - 1), (k - cutkey) >> BSHIFT);
      if ((int)bin == tb) {
        int p = atomicAdd(&sh_bcnt, 1);
        if (p < BCAP) { bkey[p] = k; bidx[p] = cidx[c]; }
      }
    }
    __syncthreads();
    const int m = sh_bcnt;
    if (m > BCAP) ok = 0;                     // guard (m), uniform

    if (ok) {
      // exact sub-rank within boundary bin; exactly one member has rank
      // need-1 (strict total order on (key desc, idx asc)) -> guard (b).
      if (tid < m) {
        const unsigned mk = bkey[tid];
        const int mi = bidx[tid];
        int rank = 0;
        for (int j = 0; j < m; ++j) {
          unsigned k = bkey[j];
          rank += (k > mk || (k == mk && bidx[j] < mi)) ? 1 : 0;
        }
        if (rank == need - 1) {
          // guard (b): K-th s-key strictly above cutoff s-key => no
          // sub-cutoff element can reach/tie the boundary (low-index ties).
          sh_ok = (tb > 0 || mk > cutkey) ? 1 : 0;
        }
        if (rank < need) {                    // boundary member of top-K
          float s = inv_fkey(mk);             // bit-exact l/temp
          float v = s + gumbel_at((uint32_t)row * (uint32_t)VOCAB + (uint32_t)mi);
          if (v > bestv || (v == bestv && mi < besti)) { bestv = v; besti = mi; }
        }
      }
      // members in bins strictly above tb are all in top-K
      for (int c = tid; c < total; c += NT) {
        unsigned k = ckey[c];
        unsigned bin = min((unsigned)(HBINS - 1), (k - cutkey) >> BSHIFT);
        if ((int)bin > tb) {
          int mi = cidx[c];
          float s = inv_fkey(k);
          float v = s + gumbel_at((uint32_t)row * (uint32_t)VOCAB + (uint32_t)mi);
          if (v > bestv || (v == bestv && mi < besti)) { bestv = v; besti = mi; }
        }
      }
      __syncthreads();                        // sh_ok settled
      if (!sh_ok) ok = 0;                     // guard (b), uniform
    }
  }

  if (ok) {
    // argmax reduction: wave shuffle + 16-way LDS combine, then done.
    for (int off = 32; off > 0; off >>= 1) {
      float v2 = __shfl_down(bestv, off);
      int i2 = __shfl_down(besti, off);
      if (v2 > bestv || (v2 == bestv && i2 < besti)) { bestv = v2; besti = i2; }
    }
    if (lane == 0) { wbv[wave] = bestv; wbi[wave] = besti; }
    __syncthreads();
    if (tid == 0) {
      float bv = wbv[0]; int bi = wbi[0];
      for (int w = 1; w < 16; ++w) {
        if (wbv[w] > bv || (wbv[w] == bv && wbi[w] < bi)) { bv = wbv[w]; bi = wbi[w]; }
      }
      out[row] = bi;
    }
    return;                                   // block-uniform
  }

  // ---- Inline fallback: verbatim round-3 two-scan histogram path ----
  {
    const float* rowp = logits + (size_t)row * VOCAB;
    const int pc = (4 - (row & 3)) & 3;
    const int nv4 = (VOCAB - pc) >> 2;
    const int tailbase = pc + (nv4 << 2);
    const int tailc = VOCAB - tailbase;
    const float4* body = (const float4*)(rowp + pc);

    bestv = -__builtin_huge_valf();
    besti = 0x7fffffff;

    uint32_t filt = fkey(FILTER_VAL);
    int tb = 0;
    for (;;) {
      for (int b = tid; b < NBINS; b += NT) hist[b] = 0u;
      __syncthreads();
      if (tid < pc) {
        uint32_t k = fkey(rowp[tid]);
        if (k >= filt) atomicAdd(&hist[k >> 20], 1u);
      }
      for (int w = tid; w < nv4; w += NT) {
        float4 x = body[w];
        uint32_t k0 = fkey(x.x), k1 = fkey(x.y), k2 = fkey(x.z), k3 = fkey(x.w);
        if (k0 >= filt) atomicAdd(&hist[k0 >> 20], 1u);
        if (k1 >= filt) atomicAdd(&hist[k1 >> 20], 1u);
        if (k2 >= filt) atomicAdd(&hist[k2 >> 20], 1u);
        if (k3 >= filt) atomicAdd(&hist[k3 >> 20], 1u);
      }
      if (tid < tailc) {
        uint32_t k = fkey(rowp[tailbase + tid]);
        if (k >= filt) atomicAdd(&hist[k >> 20], 1u);
      }
      __syncthreads();

      unsigned p = hist[4 * tid] + hist[4 * tid + 1] + hist[4 * tid + 2] + hist[4 * tid + 3];
      unsigned vv = p;
      for (int off = 1; off < 64; off <<= 1) {
        unsigned o = (unsigned)__shfl_down((int)vv, off);
        if (lane + off < 64) vv += o;         // inclusive suffix sum in wave
      }
      if (lane == 0) wtot[wave] = vv;
      __syncthreads();
      if (tid == 0) {
        unsigned acc = 0;
        for (int w = 15; w >= 0; --w) { aboveWave[w] = acc; acc += wtot[w]; }
        sh_total = (int)acc;
      }
      __syncthreads();
      unsigned above = aboveWave[wave] + (vv - p);
      if (above < (unsigned)K && above + p >= (unsigned)K) {
        int need = K - (int)above;
        for (int b = 3; b >= 0; --b) {
          unsigned c = hist[4 * tid + b];
          if (c >= (unsigned)need) { sh_tb = 4 * tid + b; break; }
          need -= (int)c;
        }
      }
      __syncthreads();
      if (sh_total >= K) { tb = sh_tb; break; }
      filt = 0u;
      __syncthreads();
    }

    const uint32_t cutk = (uint32_t)max(tb - 1, 0) << 20;
    if (tid == 0) sh_cnt = 0;
    __syncthreads();
    if (tid < pc) {
      if (fkey(rowp[tid]) >= cutk) {
        int p = atomicAdd(&sh_cnt, 1);
        if (p < CAND_CAP) cidx[p] = tid;
      }
    }
    for (int w = tid; w < nv4; w += NT) {
      float4 x = body[w];
      int base = pc + (w << 2);
      if (fkey(x.x) >= cutk) { int p = atomicAdd(&sh_cnt, 1); if (p < CAND_CAP) cidx[p] = base; }
      if (fkey(x.y) >= cutk) { int p = atomicAdd(&sh_cnt, 1); if (p < CAND_CAP) cidx[p] = base + 1; }
      if (fkey(x.z) >= cutk) { int p = atomicAdd(&sh_cnt, 1); if (p < CAND_CAP) cidx[p] = base + 2; }
      if (fkey(x.w) >= cutk) { int p = atomicAdd(&sh_cnt, 1); if (p < CAND_CAP) cidx[p] = base + 3; }
    }
    if (tid < tailc) {
      if (fkey(rowp[tailbase + tid]) >= cutk) {
        int p = atomicAdd(&sh_cnt, 1);
        if (p < CAND_CAP) cidx[p] = tailbase + tid;
      }
    }
    __syncthreads();
    const int C = min(sh_cnt, CAND_CAP);

    if (tid < C) {
      int idx = cidx[tid];
      float s = rowp[idx] / temp;
      ckey[tid] = fkey(s);
    }
    __syncthreads();

    if (tid < C) {
      const uint32_t mk = ckey[tid];
      const int mi = cidx[tid];
      int rank = 0;
      for (int j = 0; j < C; ++j) {
        uint32_t k = ckey[j];
        rank += (k > mk || (k == mk && cidx[j] < mi)) ? 1 : 0;
      }
      if (rank < K) {
        float s = rowp[mi] / temp;
        float v2 = s + gumbel_at((uint32_t)row * (uint32_t)VOCAB + (uint32_t)mi);
        bestv = v2; besti = mi;
      }
    }
    __syncthreads();

    for (int off = 32; off > 0; off >>= 1) {
      float v2 = __shfl_down(bestv, off);
      int i2 = __shfl_down(besti, off);
      if (v2 > bestv || (v2 == bestv && i2 < besti)) { bestv = v2; besti = i2; }
    }
    if (lane == 0) { wbv[wave] = bestv; wbi[wave] = besti; }
    __syncthreads();
    if (tid == 0) {
      float bv = wbv[0];
      int bi = wbi[0];
      for (int w = 1; w < 16; ++w) {
        if (wbv[w] > bv || (wbv[w] == bv && wbi[w] < bi)) { bv = wbv[w]; bi = wbi[w]; }
      }
      out[row] = bi;
    }
  }
}

extern "C" void kernel_launch(void* const* d_in, const int* in_sizes, int n_in,
                              void* d_out, int out_size, void* d_ws, size_t ws_size,
                              hipStream_t stream) {
  const float* logits = (const float*)d_in[0];
  const float* temp_p = (const float*)d_in[1];
  const int* topk_p = (const int*)d_in[2];
  int* out = (int*)d_out;

  // workspace: cnt[4096] | cand_idx[4096*64] | cand_val[4096*64]  (~2.02 MB)
  int* cnt = (int*)d_ws;
  int* cand_idx = cnt + BATCH * NSEG;
  float* cand_val = (float*)(cand_idx + BATCH * NSEG * CAP_SEG);

  hipLaunchKernelGGL(filter_kernel, dim3(BATCH * NSEG), dim3(NTF), 0, stream,
                     logits, cnt, cand_idx, cand_val);
  hipLaunchKernelGGL(refine_kernel, dim3(BATCH), dim3(NT), 0, stream,
                     logits, temp_p, topk_p, out, cnt, cand_idx, cand_val);
}